// Round 8
// baseline (384.993 us; speedup 1.0000x reference)
//
#include <hip/hip_runtime.h>
#include <cfloat>
#include <climits>
#include <math.h>

// Problem constants
#define BB 2048
#define NN 50000
#define DD 128
#define KK 20

// K1 selection geometry
#define NSLICE 16
#define NSL 3125          // NN / NSLICE (exact)
#define NTILE 98          // ceil(NSL/32); tile 97 partial (21 valid entries)
#define TAILV 21          // NSL - (NTILE-1)*32 valid entries in last tile
#define LK 8              // per-lane sorted key slots
#define CAND 256          // candidates per row per task (32 streams x 8)
#define K1W 4             // waves per k1 block (tile-split, LDS-merged)

// out layout (floats): vals_cos, ind_cos, labels_rot, vals_euc, ind_euc, labels_trans
#define O_VC 0
#define O_IC 40960
#define O_LR 81920
#define O_VE 122880
#define O_IE 163840
#define O_LT 204800

// ws layout (bytes):
//   Bbf  (fragment-ordered bf16 books)      25,690,112
//   bq2  (packed -bq hi/lo bf16)               200,000  (at 25,690,112)
//   candT (top-4 full keys / stream, uint4)  2,097,152  (at 25,890,112)
//   candB (bottom-4 12-bit locals, 3xu16)      786,432  (at 27,987,264)
//   end = 28,773,696  <= 28.81 MB proven
#define WS_BBF   0
#define WS_BQ2   25690112
#define WS_CANDT 25890112
#define WS_CANDB 27987264

typedef short v8s __attribute__((ext_vector_type(8)));
typedef float v16f __attribute__((ext_vector_type(16)));

union U4V8 { uint4 u; v8s v; };

__device__ __forceinline__ unsigned int bf16rne(float f) {
    unsigned int x = __float_as_uint(f);
    return (x + 0x7FFFu + ((x >> 16) & 1u)) >> 16;
}
// monotone fp32 -> u32 (total order)
__device__ __forceinline__ unsigned int sortkey(float s) {
    unsigned int b = __float_as_uint(s);
    return b ^ ((unsigned int)((int)b >> 31) | 0x80000000u);
}
// inverse of sortkey (works on hi-16-truncated keys; truncation is toward -inf)
__device__ __forceinline__ float unkey(unsigned int k) {
    unsigned int b = (k & 0x80000000u) ? (k ^ 0x80000000u) : ~k;
    return __uint_as_float(b);
}
// compare-exchange
__device__ __forceinline__ void ce(unsigned int &a, unsigned int &b) {
    unsigned int lo = min(a, b);
    unsigned int hi = max(a, b);
    a = lo; b = hi;
}
// Batcher odd-even mergesort-8, ascending (19 CEs, depth 6)
__device__ __forceinline__ void sort8(unsigned int* k) {
    ce(k[0],k[1]); ce(k[2],k[3]); ce(k[4],k[5]); ce(k[6],k[7]);
    ce(k[0],k[2]); ce(k[1],k[3]); ce(k[4],k[6]); ce(k[5],k[7]);
    ce(k[1],k[2]); ce(k[5],k[6]);
    ce(k[0],k[4]); ce(k[1],k[5]); ce(k[2],k[6]); ce(k[3],k[7]);
    ce(k[2],k[4]); ce(k[3],k[5]);
    ce(k[1],k[2]); ce(k[3],k[4]); ce(k[5],k[6]);
}
// run asc, s asc -> run = top-8 of (run ∪ s), ascending (8 max + 12-CE bitonic)
__device__ __forceinline__ void merge8(unsigned int (&run)[LK], const unsigned int* s) {
    unsigned int m[8];
    #pragma unroll
    for (int i = 0; i < 8; i++) m[i] = max(run[i], s[7 - i]);
    ce(m[0],m[4]); ce(m[1],m[5]); ce(m[2],m[6]); ce(m[3],m[7]);
    ce(m[0],m[2]); ce(m[1],m[3]); ce(m[4],m[6]); ce(m[5],m[7]);
    ce(m[0],m[1]); ce(m[2],m[3]); ce(m[4],m[5]); ce(m[6],m[7]);
    #pragma unroll
    for (int i = 0; i < 8; i++) run[i] = m[i];
}

// ---------------- K0: build bf16 book in MFMA-FRAGMENT ORDER + packed -bq ----------
__global__ __launch_bounds__(256) void k_cvt2(const float* __restrict__ bR,
                                              const float* __restrict__ bT,
                                              unsigned int* __restrict__ Bbf,
                                              unsigned int* __restrict__ bq2)
{
    const int tile  = blockIdx.x;   // 0..97
    const int slice = blockIdx.y;   // 0..15
    const int task  = blockIdx.z;
    const int t = threadIdx.x;
    const float* __restrict__ src = task ? bT : bR;
    const float sc = task ? 2.f : 1.f;

    __shared__ float ps[4][64];

    unsigned int* tb = Bbf + (((size_t)(task * NSLICE + slice) * NTILE + tile) << 11);

    float partial = 0.f;
    #pragma unroll
    for (int half = 0; half < 2; half++) {
        const int x = t + half * 256;
        const int c = x & 31, hh = (x >> 5) & 1, q = x >> 6;
        const int es = slice * NSL + min(tile * 32 + c, NSL - 1);
        const float* p = src + (size_t)es * DD + q * 16 + hh * 8;
        float4 u0 = *reinterpret_cast<const float4*>(p);
        float4 u1 = *reinterpret_cast<const float4*>(p + 4);
        partial += u0.x * u0.x + u0.y * u0.y + u0.z * u0.z + u0.w * u0.w
                 + u1.x * u1.x + u1.y * u1.y + u1.z * u1.z + u1.w * u1.w;
        uint4 o;
        o.x = bf16rne(u0.x * sc) | (bf16rne(u0.y * sc) << 16);
        o.y = bf16rne(u0.z * sc) | (bf16rne(u0.w * sc) << 16);
        o.z = bf16rne(u1.x * sc) | (bf16rne(u1.y * sc) << 16);
        o.w = bf16rne(u1.z * sc) | (bf16rne(u1.w * sc) << 16);
        *reinterpret_cast<uint4*>(tb + (q << 8) + hh * 128 + c * 4) = o;
    }

    if (task) {
        ps[t >> 6][t & 63] = partial;
        __syncthreads();
        if (t < 32) {
            float sq = 0.f;
            #pragma unroll
            for (int w2 = 0; w2 < 4; w2++) sq += ps[w2][t] + ps[w2][t + 32];
            unsigned int hi = bf16rne(sq);
            float fhi = __uint_as_float(hi << 16);
            unsigned int lo = bf16rne(sq - fhi);
            const int e = slice * NSL + min(tile * 32 + t, NSL - 1);
            bq2[e] = (hi ^ 0x8000u) | ((lo ^ 0x8000u) << 16);  // packed (-bq_hi, -bq_lo)
        }
    }
}

// ---------------- K1: MFMA scoring, z-frags in LDS, Batcher-network top-8 ----------
// LDS-z (R4) + sort16/merge networks (R3) now that registers are free (grid = 8
// blocks/CU, VGPR budget 64). Writeout: per stream, top-4 FULL keys (score16|idx16)
// + bottom-4 12-bit local indices -> enables margin-pruned exact rescore in K2.
__global__ __launch_bounds__(256, 8) void k1_sel(
    const float* __restrict__ zR, const float* __restrict__ zT,
    const unsigned int* __restrict__ Bbf,
    const unsigned int* __restrict__ bq2,
    uint4* __restrict__ candT, unsigned short* __restrict__ candB)
{
    const int slice = blockIdx.x;       // 0..15
    const int rg    = blockIdx.y;       // 0..63
    const int task  = blockIdx.z;
    const int w     = threadIdx.x >> 6; // wave 0..3
    const int lane  = threadIdx.x & 63;
    const int col   = lane & 31;
    const int h     = lane >> 5;

    __shared__ uint4 zs[8][64];                         // 8 KB shared z-frags
    __shared__ unsigned int smk[K1W - 1][64][LK + 1];   // stride-9 pad, 6.75 KB

    if (w == 0) {
        const float* zp = (task ? zT : zR) + (size_t)(rg * 32 + col) * DD;
        #pragma unroll
        for (int q = 0; q < 8; q++) {
            float4 u0 = *reinterpret_cast<const float4*>(zp + q * 16 + h * 8);
            float4 u1 = *reinterpret_cast<const float4*>(zp + q * 16 + h * 8 + 4);
            uint4 c;
            c.x = bf16rne(u0.x) | (bf16rne(u0.y) << 16);
            c.y = bf16rne(u0.z) | (bf16rne(u0.w) << 16);
            c.z = bf16rne(u1.x) | (bf16rne(u1.y) << 16);
            c.w = bf16rne(u1.z) | (bf16rne(u1.w) << 16);
            zs[q][lane] = c;
        }
    }
    U4V8 zf8; zf8.u = make_uint4(h == 0 ? 0x3F803F80u : 0u, 0u, 0u, 0u);
    __syncthreads();

    unsigned int run[LK];
    #pragma unroll
    for (int u = 0; u < LK; u++) run[u] = 0u;

    const int nbase0 = slice * NSL;
    const unsigned int* bp = Bbf + ((size_t)(task * NSLICE + slice) * NTILE << 11) + lane * 4;

#define TILE_BODY(TILE, TAIL)                                                          \
    {                                                                                  \
        asm volatile("" ::: "memory");  /* keep zs reads per-tile (no 32-reg hoist) */ \
        const unsigned int* tb = bp + ((size_t)(TILE) << 11);                          \
        v16f acc = {0.f,0.f,0.f,0.f, 0.f,0.f,0.f,0.f,                                  \
                    0.f,0.f,0.f,0.f, 0.f,0.f,0.f,0.f};                                 \
        _Pragma("unroll")                                                              \
        for (int q = 0; q < 8; q++) {                                                  \
            U4V8 a; a.u = *reinterpret_cast<const uint4*>(tb + (q << 8));              \
            U4V8 z; z.u = zs[q][lane];                                                 \
            acc = __builtin_amdgcn_mfma_f32_32x32x16_bf16(a.v, z.v, acc, 0, 0, 0);     \
        }                                                                              \
        if (task) {                                                                    \
            int e = nbase0 + (TILE) * 32 + col;                                        \
            if (TAIL) e = min(e, nbase0 + NSL - 1);                                    \
            unsigned int bqp = bq2[e];                                                 \
            U4V8 a; a.u = make_uint4(h == 0 ? bqp : 0u, 0u, 0u, 0u);                   \
            acc = __builtin_amdgcn_mfma_f32_32x32x16_bf16(a.v, zf8.v, acc, 0, 0, 0);   \
        }                                                                              \
        const int nb = nbase0 + (TILE) * 32 + 4 * h;                                   \
        unsigned int kk[16];                                                           \
        _Pragma("unroll")                                                              \
        for (int r = 0; r < 16; r++) {                                                 \
            const int pat = (r & 3) + 8 * (r >> 2);                                    \
            const int n = nb + pat;                                                    \
            unsigned int k = (sortkey(acc[r]) & 0xFFFF0000u) | (unsigned int)n;        \
            if (TAIL && (pat + 4 * h >= TAILV)) k = 0u;                                \
            kk[r] = k;                                                                 \
        }                                                                              \
        sort8(&kk[0]); sort8(&kk[8]);                                                  \
        merge8(run, &kk[0]); merge8(run, &kk[8]);                                      \
    }

    int tile = w;
    for (; tile < NTILE - 1; tile += K1W) TILE_BODY(tile, 0)
    if (tile == NTILE - 1) TILE_BODY(tile, 1)
#undef TILE_BODY

    if (w > 0) {
        #pragma unroll
        for (int u = 0; u < LK; u++) smk[w - 1][lane][u] = run[u];
    }
    __syncthreads();
    if (w == 0) {
        #pragma unroll
        for (int v = 0; v < K1W - 1; v++) {
            unsigned int s[LK];
            #pragma unroll
            for (int u = 0; u < LK; u++) s[u] = smk[v][lane][u];
            merge8(run, s);
        }

        // ---- writeout: top-4 full keys (desc) + bottom-4 12-bit locals ----
        const int row = rg * 32 + col;
        const size_t strm = (((size_t)(task * BB + row) * NSLICE + slice) << 1) + h;
        candT[strm] = make_uint4(run[7], run[6], run[5], run[4]);
        unsigned long long V =
              (unsigned long long)((run[3] & 0xFFFFu) - (unsigned)nbase0)
            | ((unsigned long long)((run[2] & 0xFFFFu) - (unsigned)nbase0) << 12)
            | ((unsigned long long)((run[1] & 0xFFFFu) - (unsigned)nbase0) << 24)
            | ((unsigned long long)((run[0] & 0xFFFFu) - (unsigned)nbase0) << 36);
        candB[strm * 3 + 0] = (unsigned short)V;
        candB[strm * 3 + 1] = (unsigned short)(V >> 16);
        candB[strm * 3 + 2] = (unsigned short)(V >> 32);
    }
}

// ---------------- K2: margin-pruned exact rescore + top-20 + gather ----------------
// Phase 1: 20th-best approx key t20 from the 128 stored keys (subset => t20' <= t20,
//   threshold only gets safer). Margin M >= 2*max|approx-exact| + key truncation:
//   |err| <= 2^-8*||z||*||b|| (C-S over bf16 rne; ||b||=1 cos, ||b||^2<=300 euc
//   at P~1e-13) + 2^-6*|t20|. A pruned candidate's exact score is strictly below
//   >=20 others' => cannot enter (or tie into) the exact top-20.
// Phase 2: rescore kept (~25-40 of 256) exactly; others -inf. Streams' bottom-4 are
//   <= their rank-4 key => one compare prunes all four.
// Phase 3: unchanged 20-round exact tournament + label gather => output identical.
__global__ __launch_bounds__(256) void k2_final(
    const float* __restrict__ Zr, const float* __restrict__ Zt,
    const float* __restrict__ Br, const float* __restrict__ Bt,
    const float* __restrict__ rotB, const float* __restrict__ transB,
    const unsigned int* __restrict__ candT32,
    const unsigned short* __restrict__ candB,
    float* __restrict__ out)
{
    const int row = blockIdx.x;
    const int task = blockIdx.y;
    const int t = threadIdx.x;
    const float* __restrict__ Z  = task ? Zt : Zr;
    const float* __restrict__ Bk = task ? Bt : Br;

    __shared__ __align__(16) float zrow[DD];
    __shared__ unsigned int keyT[128];
    __shared__ double dsc[CAND];
    __shared__ float svc[CAND];
    __shared__ int sidn[CAND];
    __shared__ double sval[KK];
    __shared__ int sidx[KK];
    __shared__ float thr;
    __shared__ double zqs;

    if (t < DD) zrow[t] = Z[(size_t)row * DD + t];
    if (t < 128) keyT[t] = candT32[(size_t)(task * BB + row) * 128 + t];
    __syncthreads();

    // ---- Phase 1: wave 0 finds t20 (20th-best of 128 keys) + ||z||^2 + threshold ----
    if (t < 64) {
        double zq = (double)zrow[t] * (double)zrow[t]
                  + (double)zrow[t + 64] * (double)zrow[t + 64];
        #pragma unroll
        for (int m = 1; m < 64; m <<= 1) zq += __shfl_xor(zq, m, 64);

        unsigned int a = keyT[t], b = keyT[t + 64];
        unsigned int t20 = 0u;
        for (int rd = 0; rd < KK; rd++) {
            unsigned int mx = max(a, b);
            #pragma unroll
            for (int m = 1; m < 64; m <<= 1)
                mx = max(mx, (unsigned int)__shfl_xor((int)mx, m, 64));
            if (a == mx) a = 0u;      // keys unique (idx in low bits)
            if (b == mx) b = 0u;
            t20 = mx;
        }
        if (t == 0) {
            zqs = zq;
            const float s20 = unkey(t20 & 0xFFFF0000u);
            const float nz = sqrtf((float)zq);
            const float Bm = task ? (0.14f * nz + 0.05f) : (0.0045f * nz + 0.001f);
            thr = s20 - 2.f * Bm - 0.016f * fabsf(s20) - (task ? 0.1f : 1e-3f);
        }
    }
    __syncthreads();

    // ---- Phase 2: per-candidate keep decision + exact rescore ----
    {
        const int c = t, s = c >> 3, r = c & 7, slice = s >> 1;
        const float thv = thr;
        bool keep;
        int idx;
        if (r < 4) {
            const unsigned int k = keyT[s * 4 + r];
            idx = (int)(k & 0xFFFFu);
            keep = unkey(k & 0xFFFF0000u) >= thv;
        } else {
            const unsigned short* cb = candB + ((size_t)(task * BB + row) * 32 + s) * 3;
            unsigned long long V = (unsigned long long)cb[0]
                | ((unsigned long long)cb[1] << 16)
                | ((unsigned long long)cb[2] << 32);
            idx = slice * NSL + (int)((V >> (12 * (r - 4))) & 0xFFFu);
            keep = unkey(keyT[s * 4 + 3] & 0xFFFF0000u) >= thv;   // bottom-4 <= rank-4
        }
        sidn[c] = idx;

        if (task == 0) {
            double dp = -DBL_MAX;
            if (keep) {
                const float* brow = Bk + (size_t)idx * DD;
                dp = 0.0;
                #pragma unroll
                for (int q = 0; q < 32; q++) {
                    float4 b4 = *reinterpret_cast<const float4*>(brow + q * 4);
                    float4 z4 = *reinterpret_cast<const float4*>(&zrow[q * 4]);
                    dp += (double)z4.x * (double)b4.x + (double)z4.y * (double)b4.y
                        + (double)z4.z * (double)b4.z + (double)z4.w * (double)b4.w;
                }
            }
            dsc[c] = dp;
        } else {
            float v = -FLT_MAX;
            if (keep) {
                // bit-exact numpy-fp32 emulation (verified R3/R4)
                const float* brow = Bk + (size_t)idx * DD;
                float L[4], rr[8], qq[8];
                #pragma unroll
                for (int u = 0; u < 4; u++) L[u] = 0.f;
                #pragma unroll
                for (int u = 0; u < 8; u++) { rr[u] = 0.f; qq[u] = 0.f; }
                #pragma unroll
                for (int c4 = 0; c4 < 32; c4++) {
                    float4 b4 = *reinterpret_cast<const float4*>(brow + c4 * 4);
                    float4 z4 = *reinterpret_cast<const float4*>(&zrow[c4 * 4]);
                    const int m8 = (c4 & 1) * 4;
                    L[0] = __fadd_rn(L[0], __fmul_rn(z4.x, b4.x));
                    L[1] = __fadd_rn(L[1], __fmul_rn(z4.y, b4.y));
                    L[2] = __fadd_rn(L[2], __fmul_rn(z4.z, b4.z));
                    L[3] = __fadd_rn(L[3], __fmul_rn(z4.w, b4.w));
                    rr[m8 + 0] = __fadd_rn(rr[m8 + 0], __fmul_rn(b4.x, b4.x));
                    rr[m8 + 1] = __fadd_rn(rr[m8 + 1], __fmul_rn(b4.y, b4.y));
                    rr[m8 + 2] = __fadd_rn(rr[m8 + 2], __fmul_rn(b4.z, b4.z));
                    rr[m8 + 3] = __fadd_rn(rr[m8 + 3], __fmul_rn(b4.w, b4.w));
                    qq[m8 + 0] = __fadd_rn(qq[m8 + 0], __fmul_rn(z4.x, z4.x));
                    qq[m8 + 1] = __fadd_rn(qq[m8 + 1], __fmul_rn(z4.y, z4.y));
                    qq[m8 + 2] = __fadd_rn(qq[m8 + 2], __fmul_rn(z4.z, z4.z));
                    qq[m8 + 3] = __fadd_rn(qq[m8 + 3], __fmul_rn(z4.w, z4.w));
                }
                const float dot = __fadd_rn(__fadd_rn(L[0], L[2]), __fadd_rn(L[1], L[3]));
                const float bqv = __fadd_rn(
                    __fadd_rn(__fadd_rn(rr[0], rr[1]), __fadd_rn(rr[2], rr[3])),
                    __fadd_rn(__fadd_rn(rr[4], rr[5]), __fadd_rn(rr[6], rr[7])));
                const float zqv = __fadd_rn(
                    __fadd_rn(__fadd_rn(qq[0], qq[1]), __fadd_rn(qq[2], qq[3])),
                    __fadd_rn(__fadd_rn(qq[4], qq[5]), __fadd_rn(qq[6], qq[7])));
                v = __fsub_rn(__fsub_rn(__fmul_rn(2.0f, dot), zqv), bqv);
            }
            svc[c] = v;
        }
    }
    __syncthreads();

    // ---- Phase 3: exact top-20 tournament (unchanged logic) + outputs ----
    if (t < 64) {
        if (task == 0) {
            double s[4]; int ix[4];
            #pragma unroll
            for (int j = 0; j < 4; j++) {
                const int cc = t + 64 * j;
                s[j] = dsc[cc]; ix[j] = sidn[cc];
            }
            for (int rd = 0; rd < KK; rd++) {
                double bs = s[0]; int bn = ix[0];
                #pragma unroll
                for (int j = 1; j < 4; j++)
                    if (s[j] > bs || (s[j] == bs && ix[j] < bn)) { bs = s[j]; bn = ix[j]; }
                #pragma unroll
                for (int m = 1; m < 64; m <<= 1) {
                    double os = __shfl_xor(bs, m, 64);
                    int on = __shfl_xor(bn, m, 64);
                    if (os > bs || (os == bs && on < bn)) { bs = os; bn = on; }
                }
                #pragma unroll
                for (int j = 0; j < 4; j++) if (ix[j] == bn) s[j] = -DBL_MAX;  // pop
                if (t == 0) { sval[rd] = bs; sidx[rd] = bn; }
            }
        } else {
            float s[4]; int ix[4];
            #pragma unroll
            for (int j = 0; j < 4; j++) {
                const int cc = t + 64 * j;
                s[j] = svc[cc]; ix[j] = sidn[cc];
            }
            for (int rd = 0; rd < KK; rd++) {
                float bs = s[0]; int bn = ix[0];
                #pragma unroll
                for (int j = 1; j < 4; j++)
                    if (s[j] > bs || (s[j] == bs && ix[j] < bn)) { bs = s[j]; bn = ix[j]; }
                #pragma unroll
                for (int m = 1; m < 64; m <<= 1) {
                    float os = __shfl_xor(bs, m, 64);
                    int on = __shfl_xor(bn, m, 64);
                    if (os > bs || (os == bs && on < bn)) { bs = os; bn = on; }
                }
                #pragma unroll
                for (int j = 0; j < 4; j++) if (ix[j] == bn) s[j] = -FLT_MAX;
                if (t == 0) {
                    const int o = row * KK + rd;
                    out[O_VE + o] = bs;
                    out[O_IE + o] = (float)bn;
                    const int o3 = O_LT + o * 3;
                    out[o3 + 0] = transB[bn * 3 + 0];
                    out[o3 + 1] = transB[bn * 3 + 1];
                    out[o3 + 2] = transB[bn * 3 + 2];
                }
            }
        }
    }
    __syncthreads();

    if (task == 0 && t < KK) {
        const int n = sidx[t];
        const int o = row * KK + t;
        out[O_VC + o] = (float)(sval[t] / sqrt(zqs));
        out[O_IC + o] = (float)n;
        out[O_LR + o] = rotB[n];
    }
}

// ---------------- launch ------------------------------------------------------------
extern "C" void kernel_launch(void* const* d_in, const int* in_sizes, int n_in,
                              void* d_out, int out_size, void* d_ws, size_t ws_size,
                              hipStream_t stream) {
    const float* zR = (const float*)d_in[0];
    const float* zT = (const float*)d_in[1];
    const float* bR = (const float*)d_in[2];
    const float* bT = (const float*)d_in[3];
    const float* rotB = (const float*)d_in[4];
    const float* transB = (const float*)d_in[5];
    float* out = (float*)d_out;

    char* ws = (char*)d_ws;
    unsigned int* Bbf = (unsigned int*)(ws + WS_BBF);
    unsigned int* bq2 = (unsigned int*)(ws + WS_BQ2);
    uint4* candT = (uint4*)(ws + WS_CANDT);
    unsigned short* candB = (unsigned short*)(ws + WS_CANDB);

    k_cvt2<<<dim3(NTILE, NSLICE, 2), 256, 0, stream>>>(bR, bT, Bbf, bq2);
    k1_sel<<<dim3(NSLICE, 64, 2), 256, 0, stream>>>(zR, zT, Bbf, bq2, candT, candB);
    k2_final<<<dim3(BB, 2), 256, 0, stream>>>(zR, zT, bR, bT, rotB, transB,
                                              (const unsigned int*)candT, candB, out);
}

// Round 11
// 330.155 us; speedup vs baseline: 1.1661x; 1.1661x over previous
//
#include <hip/hip_runtime.h>
#include <cfloat>
#include <climits>
#include <math.h>

// Problem constants
#define BB 2048
#define NN 50000
#define DD 128
#define KK 20

// K1 selection geometry
#define NSLICE 16
#define NSL 3125          // NN / NSLICE (exact)
#define NTILE 98          // ceil(NSL/32); tile 97 partial (21 valid entries)
#define TAILV 21          // NSL - (NTILE-1)*32 valid entries in last tile
#define LK 8              // per-lane sorted key slots
#define SLC 16            // per (row,slice) stored candidates (2 lanes x LK)
#define CAND 256          // NSLICE * SLC per row per task
#define K1W 4             // waves per k1 block (tile-split, LDS-merged)

// out layout (floats): vals_cos, ind_cos, labels_rot, vals_euc, ind_euc, labels_trans
#define O_VC 0
#define O_IC 40960
#define O_LR 81920
#define O_VE 122880
#define O_IE 163840
#define O_LT 204800

// ws layout (bytes): Bbf 25.69MB | bq2 200KB | candU 2.1MB
#define WS_BBF   0
#define WS_BQ2   25690112
#define WS_CAND  25890112
// k2 score scratch ALIASES the Bbf region: k2a runs stream-ordered after k1_sel's
// last read of Bbf, and k_cvt2 rewrites Bbf at the start of every launch. Safe.
#define WS_DSUM  0          // 2048*256*8B = 4.19 MB (fp64 cos rescores)
#define WS_SV    4194304    // 2048*256*4B = 2.10 MB (fp32 euc rescores)

typedef short v8s __attribute__((ext_vector_type(8)));
typedef float v16f __attribute__((ext_vector_type(16)));

union U4V8 { uint4 u; v8s v; };

__device__ __forceinline__ unsigned int bf16rne(float f) {
    unsigned int x = __float_as_uint(f);
    return (x + 0x7FFFu + ((x >> 16) & 1u)) >> 16;
}
// monotone fp32 -> u32 (total order)
__device__ __forceinline__ unsigned int sortkey(float s) {
    unsigned int b = __float_as_uint(s);
    return b ^ ((unsigned int)((int)b >> 31) | 0x80000000u);
}
// single-instruction sorted-insert step: med3(k, key[u], key[u+1]) ==
// min(key[u+1], max(k, key[u])) under the sortedness invariant key[u] <= key[u+1]
__device__ __forceinline__ unsigned int med3u(unsigned int a, unsigned int b, unsigned int c) {
    unsigned int d;
    asm("v_med3_u32 %0, %1, %2, %3" : "=v"(d) : "v"(a), "v"(b), "v"(c));
    return d;
}
// low-register-pressure top-8 insert (consumes one key at a time; run ascending)
__device__ __forceinline__ void ins8(unsigned int (&run)[LK], unsigned int k) {
    #pragma unroll
    for (int u = 0; u < LK - 1; u++) run[u] = med3u(k, run[u], run[u + 1]);
    run[LK - 1] = max(k, run[LK - 1]);
}
// compare-exchange (for the block-merge network only)
__device__ __forceinline__ void ce(unsigned int &a, unsigned int &b) {
    unsigned int lo = min(a, b);
    unsigned int hi = max(a, b);
    a = lo; b = hi;
}
// run asc, s asc -> run = top-8 of (run ∪ s), ascending (8 max + 12-CE bitonic)
__device__ __forceinline__ void merge8(unsigned int (&run)[LK], const unsigned int* s) {
    unsigned int m[8];
    #pragma unroll
    for (int i = 0; i < 8; i++) m[i] = max(run[i], s[7 - i]);
    ce(m[0],m[4]); ce(m[1],m[5]); ce(m[2],m[6]); ce(m[3],m[7]);
    ce(m[0],m[2]); ce(m[1],m[3]); ce(m[4],m[6]); ce(m[5],m[7]);
    ce(m[0],m[1]); ce(m[2],m[3]); ce(m[4],m[5]); ce(m[6],m[7]);
    #pragma unroll
    for (int i = 0; i < 8; i++) run[i] = m[i];
}

// ---------------- K0: build bf16 book in MFMA-FRAGMENT ORDER + packed -bq ----------
__global__ __launch_bounds__(256) void k_cvt2(const float* __restrict__ bR,
                                              const float* __restrict__ bT,
                                              unsigned int* __restrict__ Bbf,
                                              unsigned int* __restrict__ bq2)
{
    const int tile  = blockIdx.x;   // 0..97
    const int slice = blockIdx.y;   // 0..15
    const int task  = blockIdx.z;
    const int t = threadIdx.x;
    const float* __restrict__ src = task ? bT : bR;
    const float sc = task ? 2.f : 1.f;

    __shared__ float ps[4][64];

    unsigned int* tb = Bbf + (((size_t)(task * NSLICE + slice) * NTILE + tile) << 11);

    float partial = 0.f;
    #pragma unroll
    for (int half = 0; half < 2; half++) {
        const int x = t + half * 256;
        const int c = x & 31, hh = (x >> 5) & 1, q = x >> 6;
        const int es = slice * NSL + min(tile * 32 + c, NSL - 1);
        const float* p = src + (size_t)es * DD + q * 16 + hh * 8;
        float4 u0 = *reinterpret_cast<const float4*>(p);
        float4 u1 = *reinterpret_cast<const float4*>(p + 4);
        partial += u0.x * u0.x + u0.y * u0.y + u0.z * u0.z + u0.w * u0.w
                 + u1.x * u1.x + u1.y * u1.y + u1.z * u1.z + u1.w * u1.w;
        uint4 o;
        o.x = bf16rne(u0.x * sc) | (bf16rne(u0.y * sc) << 16);
        o.y = bf16rne(u0.z * sc) | (bf16rne(u0.w * sc) << 16);
        o.z = bf16rne(u1.x * sc) | (bf16rne(u1.y * sc) << 16);
        o.w = bf16rne(u1.z * sc) | (bf16rne(u1.w * sc) << 16);
        *reinterpret_cast<uint4*>(tb + (q << 8) + hh * 128 + c * 4) = o;
    }

    if (task) {
        ps[t >> 6][t & 63] = partial;
        __syncthreads();
        if (t < 32) {
            float sq = 0.f;
            #pragma unroll
            for (int w2 = 0; w2 < 4; w2++) sq += ps[w2][t] + ps[w2][t + 32];
            unsigned int hi = bf16rne(sq);
            float fhi = __uint_as_float(hi << 16);
            unsigned int lo = bf16rne(sq - fhi);
            const int e = slice * NSL + min(tile * 32 + t, NSL - 1);
            bq2[e] = (hi ^ 0x8000u) | ((lo ^ 0x8000u) << 16);  // packed (-bq_hi, -bq_lo)
        }
    }
}

// ---------------- K1: MFMA scoring, z-frags in LDS, med3-chain top-8 ---------------
// R7's validated kernel; ONLY change: tile loop unrolled x2 with one memory barrier
// per unrolled iteration (zs LDS reads CSE'd across the pair, 16 global loads in
// flight). Per-wave tile order unchanged (w, w+K1W, ...) => candU bit-identical.
__global__ __launch_bounds__(256, 8) void k1_sel(
    const float* __restrict__ zR, const float* __restrict__ zT,
    const unsigned int* __restrict__ Bbf,
    const unsigned int* __restrict__ bq2,
    uint4* __restrict__ candU)
{
    const int slice = blockIdx.x;       // 0..15
    const int rg    = blockIdx.y;       // 0..63
    const int task  = blockIdx.z;
    const int w     = threadIdx.x >> 6; // wave 0..3
    const int lane  = threadIdx.x & 63;
    const int col   = lane & 31;
    const int h     = lane >> 5;

    __shared__ uint4 zs[8][64];                         // 8 KB shared z-frags
    __shared__ unsigned int smk[K1W - 1][64][LK + 1];   // stride-9 pad, 6.75 KB

    if (w == 0) {
        const float* zp = (task ? zT : zR) + (size_t)(rg * 32 + col) * DD;
        #pragma unroll
        for (int q = 0; q < 8; q++) {
            float4 u0 = *reinterpret_cast<const float4*>(zp + q * 16 + h * 8);
            float4 u1 = *reinterpret_cast<const float4*>(zp + q * 16 + h * 8 + 4);
            uint4 c;
            c.x = bf16rne(u0.x) | (bf16rne(u0.y) << 16);
            c.y = bf16rne(u0.z) | (bf16rne(u0.w) << 16);
            c.z = bf16rne(u1.x) | (bf16rne(u1.y) << 16);
            c.w = bf16rne(u1.z) | (bf16rne(u1.w) << 16);
            zs[q][lane] = c;
        }
    }
    U4V8 zf8; zf8.u = make_uint4(h == 0 ? 0x3F803F80u : 0u, 0u, 0u, 0u);
    __syncthreads();

    unsigned int run[LK];
    #pragma unroll
    for (int u = 0; u < LK; u++) run[u] = 0u;

    const int nbase0 = slice * NSL;
    const unsigned int* bp = Bbf + ((size_t)(task * NSLICE + slice) * NTILE << 11) + lane * 4;

#define TILE_BODY(TILE, TAIL)                                                          \
    {                                                                                  \
        const unsigned int* tb = bp + ((size_t)(TILE) << 11);                          \
        v16f acc = {0.f,0.f,0.f,0.f, 0.f,0.f,0.f,0.f,                                  \
                    0.f,0.f,0.f,0.f, 0.f,0.f,0.f,0.f};                                 \
        _Pragma("unroll")                                                              \
        for (int q = 0; q < 8; q++) {                                                  \
            U4V8 a; a.u = *reinterpret_cast<const uint4*>(tb + (q << 8));              \
            U4V8 z; z.u = zs[q][lane];                                                 \
            acc = __builtin_amdgcn_mfma_f32_32x32x16_bf16(a.v, z.v, acc, 0, 0, 0);     \
        }                                                                              \
        if (task) {                                                                    \
            int e = nbase0 + (TILE) * 32 + col;                                        \
            if (TAIL) e = min(e, nbase0 + NSL - 1);                                    \
            unsigned int bqp = bq2[e];                                                 \
            U4V8 a; a.u = make_uint4(h == 0 ? bqp : 0u, 0u, 0u, 0u);                   \
            acc = __builtin_amdgcn_mfma_f32_32x32x16_bf16(a.v, zf8.v, acc, 0, 0, 0);   \
        }                                                                              \
        const int nb = nbase0 + (TILE) * 32 + 4 * h;                                   \
        _Pragma("unroll")                                                              \
        for (int r = 0; r < 16; r++) {                                                 \
            const int pat = (r & 3) + 8 * (r >> 2);                                    \
            const int n = nb + pat;                                                    \
            unsigned int k = (sortkey(acc[r]) & 0xFFFF0000u) | (unsigned int)n;        \
            if (TAIL && (pat + 4 * h >= TAILV)) k = 0u;                                \
            ins8(run, k);                                                              \
        }                                                                              \
    }

    int tile = w;
    // unrolled x2: same per-wave visit order (w, w+K1W, w+2K1W, ...) as R7
    for (; tile + K1W <= NTILE - 2; tile += 2 * K1W) {
        asm volatile("" ::: "memory");  // keep zs reads per-iteration (no full hoist)
        TILE_BODY(tile, 0)
        TILE_BODY(tile + K1W, 0)
    }
    for (; tile < NTILE - 1; tile += K1W) {
        asm volatile("" ::: "memory");
        TILE_BODY(tile, 0)
    }
    if (tile == NTILE - 1) {
        asm volatile("" ::: "memory");
        TILE_BODY(tile, 1)
    }
#undef TILE_BODY

    if (w > 0) {
        #pragma unroll
        for (int u = 0; u < LK; u++) smk[w - 1][lane][u] = run[u];
    }
    __syncthreads();
    if (w == 0) {
        #pragma unroll
        for (int v = 0; v < K1W - 1; v++) {
            unsigned int s[LK];
            #pragma unroll
            for (int u = 0; u < LK; u++) s[u] = smk[v][lane][u];
            merge8(run, s);
        }

        uint4 o;
        o.x = (run[0] & 0xFFFFu) | ((run[1] & 0xFFFFu) << 16);
        o.y = (run[2] & 0xFFFFu) | ((run[3] & 0xFFFFu) << 16);
        o.z = (run[4] & 0xFFFFu) | ((run[5] & 0xFFFFu) << 16);
        o.w = (run[6] & 0xFFFFu) | ((run[7] & 0xFFFFu) << 16);
        const int row = rg * 32 + col;
        candU[((size_t)(task * BB + row) * NSLICE + slice) * 2 + h] = o;
    }
}

// ---------------- K2a: rescore, fully parallel, no LDS, no barriers (R7, passed) ----
__global__ __launch_bounds__(256) void k2a_rescore(
    const float* __restrict__ Zr, const float* __restrict__ Zt,
    const float* __restrict__ Br, const float* __restrict__ Bt,
    const unsigned short* __restrict__ candU16,
    double* __restrict__ dsumW, float* __restrict__ svW)
{
    const int row   = blockIdx.x;
    const int chunk = blockIdx.y;   // 0..3
    const int task  = blockIdx.z;
    const int t  = threadIdx.x;
    const int sr = t >> 2;          // candidate within chunk (0..63)
    const int sg = t & 3;           // sub-thread / component
    const int cidx = chunk * 64 + sr;
    const int n = (int)candU16[((size_t)task * BB + row) * CAND + cidx];

    if (task == 0) {
        // ---- cos: fp64 rescore, 4 threads x 32 dims, 2-level shfl reduce ----
        const float* brow = Br + (size_t)n * DD + sg * 32;
        const float* zrow = Zr + (size_t)row * DD + sg * 32;
        double dp = 0.0;
        #pragma unroll
        for (int q = 0; q < 8; q++) {
            float4 b4 = *reinterpret_cast<const float4*>(brow + q * 4);
            float4 z4 = *reinterpret_cast<const float4*>(zrow + q * 4);
            dp += (double)z4.x * (double)b4.x + (double)z4.y * (double)b4.y
                + (double)z4.z * (double)b4.z + (double)z4.w * (double)b4.w;
        }
        dp += __shfl_xor(dp, 1, 64);
        dp += __shfl_xor(dp, 2, 64);
        if (sg == 0) dsumW[(size_t)row * CAND + cidx] = dp;
    } else {
        // ---- euc: bit-exact numpy-fp32 component-split chains (verified R6/R7) ----
        const float* brow = Bt + (size_t)n * DD;
        const float* zrow = Zt + (size_t)row * DD;
        float L = 0.f, rA = 0.f, rB = 0.f, qA = 0.f, qB = 0.f;
        #pragma unroll
        for (int c4 = 0; c4 < 32; c4++) {
            const float b = brow[c4 * 4 + sg];
            const float z = zrow[c4 * 4 + sg];
            L = __fadd_rn(L, __fmul_rn(z, b));
            if ((c4 & 1) == 0) {
                rA = __fadd_rn(rA, __fmul_rn(b, b));
                qA = __fadd_rn(qA, __fmul_rn(z, z));
            } else {
                rB = __fadd_rn(rB, __fmul_rn(b, b));
                qB = __fadd_rn(qB, __fmul_rn(z, z));
            }
        }
        // dot = (L0+L2)+(L1+L3)  (fp add commutative -> same value on all 4 lanes)
        float a2 = __fadd_rn(L, __shfl_xor(L, 2, 64));
        float dot = __fadd_rn(a2, __shfl_xor(a2, 1, 64));
        // bqv = ((r0+r1)+(r2+r3)) + ((r4+r5)+(r6+r7))
        float s1 = __fadd_rn(rA, __shfl_xor(rA, 1, 64));
        float u1 = __fadd_rn(s1, __shfl_xor(s1, 2, 64));
        float s2 = __fadd_rn(rB, __shfl_xor(rB, 1, 64));
        float u2 = __fadd_rn(s2, __shfl_xor(s2, 2, 64));
        const float bqv = __fadd_rn(u1, u2);
        // zqv identical structure from q chains
        float s3 = __fadd_rn(qA, __shfl_xor(qA, 1, 64));
        float u3 = __fadd_rn(s3, __shfl_xor(s3, 2, 64));
        float s4 = __fadd_rn(qB, __shfl_xor(qB, 1, 64));
        float u4 = __fadd_rn(s4, __shfl_xor(s4, 2, 64));
        const float zqv = __fadd_rn(u3, u4);
        if (sg == 0)
            svW[(size_t)row * CAND + cidx] =
                __fsub_rn(__fsub_rn(__fmul_rn(2.0f, dot), zqv), bqv);
    }
}

// ---------------- K2b: final top-20 selection + label gather (R7, passed) -----------
__global__ __launch_bounds__(64) void k2b_final(
    const float* __restrict__ Zr,
    const float* __restrict__ rotB, const float* __restrict__ transB,
    const unsigned short* __restrict__ candU16,
    const double* __restrict__ dsumW, const float* __restrict__ svW,
    float* __restrict__ out)
{
    const int row = blockIdx.x;
    const int task = blockIdx.y;
    const int t = threadIdx.x;   // 0..63

    __shared__ double sval[KK];
    __shared__ int sidx[KK];

    const unsigned short* selp = candU16 + ((size_t)task * BB + row) * CAND;

    if (task == 0) {
        const float z0 = Zr[(size_t)row * DD + t];
        const float z1 = Zr[(size_t)row * DD + t + 64];
        double zq = (double)z0 * (double)z0 + (double)z1 * (double)z1;
        #pragma unroll
        for (int m = 1; m < 64; m <<= 1) zq += __shfl_xor(zq, m, 64);

        double s[4]; int ix[4];
        #pragma unroll
        for (int j = 0; j < 4; j++) {
            const int cc = t + 64 * j;
            s[j] = dsumW[(size_t)row * CAND + cc];
            ix[j] = (int)selp[cc];
        }

        for (int rd = 0; rd < KK; rd++) {
            double bs = s[0]; int bn = ix[0];
            #pragma unroll
            for (int j = 1; j < 4; j++)
                if (s[j] > bs || (s[j] == bs && ix[j] < bn)) { bs = s[j]; bn = ix[j]; }
            #pragma unroll
            for (int m = 1; m < 64; m <<= 1) {
                double os = __shfl_xor(bs, m, 64);
                int on = __shfl_xor(bn, m, 64);
                if (os > bs || (os == bs && on < bn)) { bs = os; bn = on; }
            }
            #pragma unroll
            for (int j = 0; j < 4; j++) if (ix[j] == bn) s[j] = -DBL_MAX;  // pop
            if (t == 0) { sval[rd] = bs; sidx[rd] = bn; }
        }
        __syncthreads();

        if (t < KK) {
            const int n = sidx[t];
            const int o = row * KK + t;
            out[O_VC + o] = (float)(sval[t] / sqrt(zq));
            out[O_IC + o] = (float)n;
            out[O_LR + o] = rotB[n];
        }
    } else {
        float s[4]; int ix[4];
        #pragma unroll
        for (int j = 0; j < 4; j++) {
            const int cc = t + 64 * j;
            s[j] = svW[(size_t)row * CAND + cc];
            ix[j] = (int)selp[cc];
        }

        for (int rd = 0; rd < KK; rd++) {
            float bs = s[0]; int bn = ix[0];
            #pragma unroll
            for (int j = 1; j < 4; j++)
                if (s[j] > bs || (s[j] == bs && ix[j] < bn)) { bs = s[j]; bn = ix[j]; }
            #pragma unroll
            for (int m = 1; m < 64; m <<= 1) {
                float os = __shfl_xor(bs, m, 64);
                int on = __shfl_xor(bn, m, 64);
                if (os > bs || (os == bs && on < bn)) { bs = os; bn = on; }
            }
            #pragma unroll
            for (int j = 0; j < 4; j++) if (ix[j] == bn) s[j] = -FLT_MAX;
            if (t == 0) {
                const int o = row * KK + rd;
                out[O_VE + o] = bs;
                out[O_IE + o] = (float)bn;
                const int o3 = O_LT + o * 3;
                out[o3 + 0] = transB[bn * 3 + 0];
                out[o3 + 1] = transB[bn * 3 + 1];
                out[o3 + 2] = transB[bn * 3 + 2];
            }
        }
    }
}

// ---------------- launch ------------------------------------------------------------
extern "C" void kernel_launch(void* const* d_in, const int* in_sizes, int n_in,
                              void* d_out, int out_size, void* d_ws, size_t ws_size,
                              hipStream_t stream) {
    const float* zR = (const float*)d_in[0];
    const float* zT = (const float*)d_in[1];
    const float* bR = (const float*)d_in[2];
    const float* bT = (const float*)d_in[3];
    const float* rotB = (const float*)d_in[4];
    const float* transB = (const float*)d_in[5];
    float* out = (float*)d_out;

    char* ws = (char*)d_ws;
    unsigned int* Bbf = (unsigned int*)(ws + WS_BBF);
    unsigned int* bq2 = (unsigned int*)(ws + WS_BQ2);
    uint4* candU = (uint4*)(ws + WS_CAND);
    double* dsumW = (double*)(ws + WS_DSUM);   // aliases Bbf (safe: stream-ordered)
    float* svW = (float*)(ws + WS_SV);

    k_cvt2<<<dim3(NTILE, NSLICE, 2), 256, 0, stream>>>(bR, bT, Bbf, bq2);
    k1_sel<<<dim3(NSLICE, 64, 2), 256, 0, stream>>>(zR, zT, Bbf, bq2, candU);
    k2a_rescore<<<dim3(BB, 4, 2), 256, 0, stream>>>(zR, zT, bR, bT,
                                                    (const unsigned short*)candU,
                                                    dsumW, svW);
    k2b_final<<<dim3(BB, 2), 64, 0, stream>>>(zR, rotB, transB,
                                              (const unsigned short*)candU,
                                              dsumW, svW, out);
}